// Round 8
// baseline (223.237 us; speedup 1.0000x reference)
//
#include <hip/hip_runtime.h>
#include <hip/hip_bf16.h>

typedef __bf16 bf16_t;
typedef __bf16 bf16x8 __attribute__((ext_vector_type(8)));
typedef __bf16 bf16x4 __attribute__((ext_vector_type(4)));
typedef float f32x4 __attribute__((ext_vector_type(4)));
typedef short short4v __attribute__((ext_vector_type(4)));

#define SEQ_T 2048
#define DMODEL 2048
#define NQH 16
#define NKVH 4
#define HDIM 128

__device__ __forceinline__ f32x4 mfma16x16x32(bf16x8 a, bf16x8 b, f32x4 c) {
  return __builtin_amdgcn_mfma_f32_16x16x32_bf16(a, b, c, 0, 0, 0);
}
__device__ __forceinline__ f32x4 mfma16x16x16(bf16x4 a, bf16x4 b, f32x4 c) {
  return __builtin_amdgcn_mfma_f32_16x16x16bf16_1k(
      __builtin_bit_cast(short4v, a), __builtin_bit_cast(short4v, b), c, 0, 0, 0);
}

typedef __attribute__((address_space(3))) void lds_void_t;
typedef __attribute__((address_space(1))) const void gbl_void_t;
__device__ __forceinline__ void gload_lds16(const bf16_t* g, bf16_t* l) {
  __builtin_amdgcn_global_load_lds((gbl_void_t*)g, (lds_void_t*)l, 16, 0, 0);
}
__device__ __forceinline__ void BAR() {
  asm volatile("" ::: "memory");
  __builtin_amdgcn_s_barrier();
  asm volatile("" ::: "memory");
}

// ---------------- cast f32 -> bf16, 8 elems/thread ----------------
__global__ __launch_bounds__(256) void cast_kernel(const float* __restrict__ src,
                                                   bf16_t* __restrict__ dst, int n8) {
  int idx = blockIdx.x * 256 + threadIdx.x;
  if (idx >= n8) return;
  const float4* s = reinterpret_cast<const float4*>(src) + (size_t)idx * 2;
  float4 a = s[0], b = s[1];
  bf16x8 r = {(bf16_t)a.x, (bf16_t)a.y, (bf16_t)a.z, (bf16_t)a.w,
              (bf16_t)b.x, (bf16_t)b.y, (bf16_t)b.z, (bf16_t)b.w};
  reinterpret_cast<bf16x8*>(dst)[idx] = r;
}

// ---------------- RoPE cos/sin table [T][64] (cos, sin) ----------------
__global__ __launch_bounds__(256) void sincos_kernel(float2* __restrict__ tab) {
  int idx = blockIdx.x * 256 + threadIdx.x;  // 2048*64
  int t = idx >> 6, i = idx & 63;
  float inv = powf(10000.0f, -(float)i * (1.0f / 64.0f));
  float ang = (float)t * inv;
  float s, c;
  sincosf(ang, &s, &c);
  tab[idx] = make_float2(c, s);
}

// ---------------- 8-phase 256xBN GEMM: C[m,n] = sum_k A[m,k]*W[n,k] ----------------
// BM=256, BK=64, 8 waves (2M x 4N). Double-buffered LDS, 4 phases per K-tile:
// {ds_read quadrant | issue 1 half-tile prefetch -> raw barrier -> setprio+16 MFMA
// -> barrier}. Counted vmcnt(2) once per K-tile (phase 0) -- loads stay in flight
// across barriers. XOR-swizzled LDS (chunk ^ row&7), pre-swizzled global source.
// MODE 0 (BN=256): QKV epilogue, RoPE fused on Q/K; V transposed + kv-permuted.
// MODE 1 (BN=128): f32 C row-major [M][2048].
template <int MODE, int BN>
__global__ __launch_bounds__(512, 2) void gemm8p(const bf16_t* __restrict__ A,
                                                 const bf16_t* __restrict__ W,
                                                 bf16_t* __restrict__ q_out,
                                                 bf16_t* __restrict__ k_out,
                                                 bf16_t* __restrict__ v_out,
                                                 float* __restrict__ c_out,
                                                 const float2* __restrict__ tab) {
  constexpr int K = 2048;
  constexpr int NT = K / 64;                  // K-tiles
  constexpr int NTX = (MODE == 0) ? (3072 / BN) : (2048 / BN);
  constexpr int WN = BN / 4;                  // wave n-extent
  constexpr int NF = WN / 16;                 // n-frags per wave
  constexpr int NFH = NF / 2;                 // n-frags per phase
  constexpr int NH = 2 + BN / 128;            // half-tiles per K-tile
  const int nwg = gridDim.x;
  const int cpx = nwg >> 3;
  const int id = ((int)blockIdx.x & 7) * cpx + ((int)blockIdx.x >> 3);
  const int m0 = (id / NTX) * 256, n0 = (id % NTX) * BN;
  const int tid = threadIdx.x;
  const int lane = tid & 63, w = tid >> 6;
  const int wr = w >> 2, wc = w & 3;
  const int l15 = lane & 15, g = lane >> 4;
  __shared__ bf16_t smem[2][(256 + BN) * 64];
  f32x4 acc[8][NF] = {};
  bf16x8 af[4][2], bfr[NFH][2];

  auto ISSUE_HALF = [&](int tt, int h) {
    const int k0 = tt * 64;
    bf16_t* base = &smem[tt & 1][0] + ((h < 2) ? h * (128 * 64) : (256 + (h - 2) * 128) * 64);
    const bf16_t* src = (h < 2) ? (A + (size_t)(m0 + h * 128) * K)
                                : (W + (size_t)(n0 + (h - 2) * 128) * K);
#pragma unroll
    for (int i = 0; i < 2; i++) {
      const int rl = i * 64 + (tid >> 3);
      gload_lds16(src + (size_t)rl * K + k0 + (((tid & 7) ^ (rl & 7)) << 3),
                  base + (i * 64 + w * 8) * 64);
    }
  };
  auto RDA = [&](const bf16_t* Ab, int qm) {
#pragma unroll
    for (int fi = 0; fi < 4; fi++) {
      const int row = wr * 128 + qm * 64 + fi * 16 + l15;
#pragma unroll
      for (int ksl = 0; ksl < 2; ksl++)
        af[fi][ksl] = *reinterpret_cast<const bf16x8*>(
            Ab + row * 64 + ((((ksl << 2) + g) ^ (row & 7)) << 3));
    }
  };
  auto RDB = [&](const bf16_t* Bb, int qn) {
#pragma unroll
    for (int fj = 0; fj < NFH; fj++) {
      const int row = wc * WN + qn * (WN / 2) + fj * 16 + l15;
#pragma unroll
      for (int ksl = 0; ksl < 2; ksl++)
        bfr[fj][ksl] = *reinterpret_cast<const bf16x8*>(
            Bb + row * 64 + ((((ksl << 2) + g) ^ (row & 7)) << 3));
    }
  };

#define MMPH(QM, QN)                                                          \
  do {                                                                        \
    __builtin_amdgcn_s_setprio(1);                                            \
    _Pragma("unroll") for (int fi = 0; fi < 4; fi++)                          \
        _Pragma("unroll") for (int fj = 0; fj < NFH; fj++)                    \
            _Pragma("unroll") for (int ksl = 0; ksl < 2; ksl++)               \
                acc[(QM)*4 + fi][(QN)*NFH + fj] = mfma16x16x32(               \
                    af[fi][ksl], bfr[fj][ksl], acc[(QM)*4 + fi][(QN)*NFH + fj]); \
    __builtin_amdgcn_s_setprio(0);                                            \
  } while (0)

  // prologue: stage tile 0
#pragma unroll
  for (int h = 0; h < NH; h++) ISSUE_HALF(0, h);

  for (int t = 0; t < NT; t++) {
    const bf16_t* Ab = &smem[t & 1][0];
    const bf16_t* Bb = Ab + 256 * 64;
    // ---- phase 0: gate tile t, prefetch h0(t+1) ----
    if (t + 1 < NT) {
      ISSUE_HALF(t + 1, 0);
      asm volatile("s_waitcnt vmcnt(2)" ::: "memory");
    } else {
      asm volatile("s_waitcnt vmcnt(0)" ::: "memory");
    }
    BAR();
    RDA(Ab, 0);
    RDB(Bb, 0);
    MMPH(0, 0);
    BAR();
    // ---- phase 1 ----
    RDB(Bb, 1);
    if (t + 1 < NT) ISSUE_HALF(t + 1, 1);
    BAR();
    MMPH(0, 1);
    BAR();
    // ---- phase 2 ----
    RDA(Ab, 1);
    if (t + 1 < NT) ISSUE_HALF(t + 1, 2);
    BAR();
    MMPH(1, 1);
    BAR();
    // ---- phase 3 ----
    RDB(Bb, 0);
    if (t + 1 < NT && NH > 3) ISSUE_HALF(t + 1, 3);
    BAR();
    MMPH(1, 0);
    BAR();
  }
#undef MMPH

  if (MODE == 0) {
#pragma unroll
    for (int fm = 0; fm < 8; fm++) {
      const int r0 = m0 + wr * 128 + fm * 16 + (g << 2);
      const int bb = r0 >> 11;
      const int tt = r0 & 2047;
#pragma unroll
      for (int fn = 0; fn < NF; fn++) {
        const int col = n0 + wc * WN + fn * 16 + l15;
        const f32x4 v = acc[fm][fn];
        if (col < 2048) {  // Q region, RoPE fused
          const int dd = col & 127;
          const float2* tp = tab + (size_t)tt * 64 + (dd >> 1);
          bf16_t* dst = q_out + (((size_t)(bb * NQH + (col >> 7)) * SEQ_T + tt) * HDIM + dd);
#pragma unroll
          for (int i = 0; i < 4; i++) {
            float me = v[i];
            float ot = __shfl_xor(me, 1);
            float2 cs = tp[(size_t)i * 64];
            float r = (dd & 1) ? (me * cs.x + ot * cs.y) : (me * cs.x - ot * cs.y);
            dst[(size_t)i * HDIM] = (bf16_t)r;
          }
        } else if (col < 2560) {  // K region, RoPE fused
          const int dd = col & 127;
          const float2* tp = tab + (size_t)tt * 64 + (dd >> 1);
          bf16_t* dst = k_out + (((size_t)(bb * NKVH + ((col - 2048) >> 7)) * SEQ_T + tt) * HDIM + dd);
#pragma unroll
          for (int i = 0; i < 4; i++) {
            float me = v[i];
            float ot = __shfl_xor(me, 1);
            float2 cs = tp[(size_t)i * 64];
            float r = (dd & 1) ? (me * cs.x + ot * cs.y) : (me * cs.x - ot * cs.y);
            dst[(size_t)i * HDIM] = (bf16_t)r;
          }
        } else {  // V region -> transposed [B,KVh,128,T'] with kv-permutation
          const int vc = col - 2560;
          const int hh = vc >> 7, dd = vc & 127;
          const int tp64 = (tt & ~63) | (((tt >> 2) & 3) << 4) | (((tt >> 4) & 3) << 2);
          bf16x4 pk = {(bf16_t)v[0], (bf16_t)v[1], (bf16_t)v[2], (bf16_t)v[3]};
          *reinterpret_cast<bf16x4*>(v_out + (((size_t)(bb * NKVH + hh) * HDIM + dd) * SEQ_T + tp64)) = pk;
        }
      }
    }
  } else {
#pragma unroll
    for (int fm = 0; fm < 8; fm++) {
      const int r0 = m0 + wr * 128 + fm * 16 + (g << 2);
#pragma unroll
      for (int fn = 0; fn < NF; fn++) {
        const int col = n0 + wc * WN + fn * 16 + l15;
#pragma unroll
        for (int i = 0; i < 4; i++) c_out[(size_t)(r0 + i) * 2048 + col] = acc[fm][fn][i];
      }
    }
  }
}

// ---------------- Flash attention (causal GQA), persistent work-stealing ----------------
// 1024 items = 32 (b,h) x 32 q-tiles of 64 rows, ordered HEAVY-FIRST
// (j = 31 - m/32). 1024 blocks x 4 waves; each wave owns 16 q-rows.
// LDS single-buffered KVBLK=64 (32 KB) -> 4 blocks/CU, 16 waves/CU: cross-block
// overlap hides stage drains + softmax chains (R7 was 1 block/CU, 2 waves/SIMD).
// Swapped QK^T -> per-lane softmax; T13 defer-max; kscale folded into exp2 fma;
// V kv-permuted global layout -> contiguous b128 PV reads.
__global__ __launch_bounds__(256, 4) void attn_kernel(const bf16_t* __restrict__ Qb,
                                                      const bf16_t* __restrict__ Kb,
                                                      const bf16_t* __restrict__ Vt,
                                                      bf16_t* __restrict__ AO,
                                                      int* __restrict__ counter) {
  __shared__ bf16_t smem[16384];  // Ks [64][128] | Vs [128][64]
  __shared__ int item_s;
  const int tid = threadIdx.x;
  const int lane = tid & 63, w = tid >> 6;
  const int l15 = lane & 15, g = lane >> 4;
  const float kscale = 0.08838834764831845f * 1.4426950408889634f;  // 1/sqrt(128)*log2e
  bf16_t* Ks = smem;
  bf16_t* Vs = smem + 8192;

  for (;;) {
    if (tid == 0) item_s = atomicAdd(counter, 1);
    __syncthreads();  // publish item; also protects smem (prev item EPI reads done)
    const int m = item_s;
    if (m >= 1024) break;
    const int j = 31 - (m >> 5);  // heavy q-tiles first
    const int bh = m & 31;
    const int b = bh >> 4, h = bh & 15, kvh = h >> 2;
    const bf16_t* Qp = Qb + (size_t)(b * NQH + h) * SEQ_T * HDIM;
    const bf16_t* Kp = Kb + (size_t)(b * NKVH + kvh) * SEQ_T * HDIM;
    const bf16_t* Vp = Vt + (size_t)(b * NKVH + kvh) * HDIM * SEQ_T;
    const int q0 = j * 64;
    const int qr = q0 + w * 16 + l15;
    bf16x8 qf[4];
#pragma unroll
    for (int c = 0; c < 4; c++)
      qf[c] = *reinterpret_cast<const bf16x8*>(Qp + (size_t)qr * HDIM + c * 32 + (g << 3));
    f32x4 o[8] = {};
    float mrun = -1e30f, lsum = 0.0f;

    for (int it = 0; it <= j; it++) {
      const int kv0 = it * 64;
      // stage K [64][128] + V [128][64] (both XOR-swizzled source, linear LDS)
#pragma unroll
      for (int cc = 0; cc < 4; cc++) {
        const int ck = cc * 256 + tid;
        const int krow = ck >> 4, kg = ck & 15;
        gload_lds16(Kp + (size_t)(kv0 + krow) * HDIM + ((kg ^ (krow & 7)) << 3),
                    Ks + (cc * 256 + w * 64) * 8);
        const int cv = cc * 256 + tid;
        const int vrow = cv >> 3, vg = cv & 7;
        gload_lds16(Vp + (size_t)vrow * SEQ_T + kv0 + ((vg ^ (vrow & 7)) << 3),
                    Vs + (cc * 256 + w * 64) * 8);
      }
      __syncthreads();  // drains vmcnt(0) via compiler waitcnt
      // ---- compute ----
      float sv[16];
      const bool noMask = (it != j);
      __builtin_amdgcn_s_setprio(1);
#pragma unroll
      for (int ksub = 0; ksub < 4; ksub++) {
        f32x4 sa = {};
        const int krow = ksub * 16 + l15;
#pragma unroll
        for (int ch = 0; ch < 4; ch++) {
          bf16x8 kf = *reinterpret_cast<const bf16x8*>(
              Ks + krow * 128 + ((((ch << 2) + g) ^ (krow & 7)) << 3));
          sa = mfma16x16x32(kf, qf[ch], sa);
        }
        if (noMask) {
#pragma unroll
          for (int i = 0; i < 4; i++) sv[ksub * 4 + i] = sa[i];
        } else {
          const int dlt = qr - kv0 - ksub * 16 - (g << 2);
#pragma unroll
          for (int i = 0; i < 4; i++) sv[ksub * 4 + i] = (i <= dlt) ? sa[i] : -3e38f;
        }
      }
      __builtin_amdgcn_s_setprio(0);
      float tm = sv[0];
#pragma unroll
      for (int jj = 1; jj < 16; jj++) tm = fmaxf(tm, sv[jj]);
      tm = fmaxf(tm, __shfl_xor(tm, 16, 64));
      tm = fmaxf(tm, __shfl_xor(tm, 32, 64));
      tm *= kscale;
      if (!__all(tm <= mrun + 8.0f)) {  // T13 defer-max
        const float mnew = fmaxf(mrun, tm);
        const float alpha = exp2f(mrun - mnew);
        mrun = mnew;
        lsum *= alpha;
#pragma unroll
        for (int dt = 0; dt < 8; dt++) o[dt] *= alpha;
      }
      float rs = 0.0f;
#pragma unroll
      for (int jj = 0; jj < 16; jj++) {
        sv[jj] = exp2f(__builtin_fmaf(sv[jj], kscale, -mrun));
        rs += sv[jj];
      }
      rs += __shfl_xor(rs, 16, 64);
      rs += __shfl_xor(rs, 32, 64);
      lsum += rs;
      bf16x4 pb[4];
#pragma unroll
      for (int ksub = 0; ksub < 4; ksub++) {
        bf16x4 t = {(bf16_t)sv[ksub * 4], (bf16_t)sv[ksub * 4 + 1],
                    (bf16_t)sv[ksub * 4 + 2], (bf16_t)sv[ksub * 4 + 3]};
        pb[ksub] = t;
      }
      __builtin_amdgcn_s_setprio(1);
#pragma unroll
      for (int dt = 0; dt < 8; dt++) {
        const int vrow = dt * 16 + l15;
#pragma unroll
        for (int s = 0; s < 2; s++) {
          bf16x8 vv = *reinterpret_cast<const bf16x8*>(
              Vs + vrow * 64 + (((2 * g + s) ^ (vrow & 7)) << 3));
          bf16x4 v0 = {vv[0], vv[1], vv[2], vv[3]};
          bf16x4 v1 = {vv[4], vv[5], vv[6], vv[7]};
          o[dt] = mfma16x16x16(v0, pb[2 * s], o[dt]);
          o[dt] = mfma16x16x16(v1, pb[2 * s + 1], o[dt]);
        }
      }
      __builtin_amdgcn_s_setprio(0);
      __syncthreads();  // all waves done reading before next stage overwrites
    }
    // epilogue: per-wave LDS slice [16 q][128 d] (wave-private), coalesced out
    const float linv = 1.0f / lsum;
    bf16_t* os = smem + w * 2048;
#pragma unroll
    for (int dt = 0; dt < 8; dt++) {
      bf16x4 pk = {(bf16_t)(o[dt][0] * linv), (bf16_t)(o[dt][1] * linv),
                   (bf16_t)(o[dt][2] * linv), (bf16_t)(o[dt][3] * linv)};
      *reinterpret_cast<bf16x4*>(os + l15 * 128 + dt * 16 + (g << 2)) = pk;
    }
    const size_t rowb = (size_t)b * SEQ_T + q0 + w * 16;
#pragma unroll
    for (int kk = 0; kk < 4; kk++) {
      const int c = lane + kk * 64;
      const int q = c >> 4, gc = c & 15;
      *reinterpret_cast<bf16x8*>(AO + (rowb + q) * DMODEL + h * HDIM + gc * 8) =
          *reinterpret_cast<const bf16x8*>(os + q * 128 + gc * 8);
    }
  }
}

extern "C" void kernel_launch(void* const* d_in, const int* in_sizes, int n_in,
                              void* d_out, int out_size, void* d_ws, size_t ws_size,
                              hipStream_t stream) {
  const float* x = (const float*)d_in[0];
  const float* Wq = (const float*)d_in[1];
  const float* Wk = (const float*)d_in[2];
  const float* Wv = (const float*)d_in[3];
  const float* Wo = (const float*)d_in[4];
  float* out = (float*)d_out;
  char* ws = (char*)d_ws;
  bf16_t* xb = (bf16_t*)(ws);                         // [4096][2048]        16 MB
  bf16_t* Wqkvb = (bf16_t*)(ws + 16777216);           // [3072][2048]        12 MB
  bf16_t* Wob = (bf16_t*)(ws + 29360128);             // [2048][2048]         8 MB
  bf16_t* Qb = (bf16_t*)(ws + 37748736);              // [2][16][2048][128]  16 MB
  bf16_t* Kb = (bf16_t*)(ws + 54525952);              // [2][4][2048][128]    4 MB
  bf16_t* Vt = (bf16_t*)(ws + 58720256);              // [2][4][128][2048]    4 MB (kv-permuted)
  bf16_t* AO = (bf16_t*)(ws + 62914560);              // [4096][2048]        16 MB
  float2* tab = (float2*)(ws + 79691776);             // [2048][64]           1 MB
  int* counter = (int*)(ws + 80740352);               // work-steal counter

  hipMemsetAsync(counter, 0, 4, stream);
  cast_kernel<<<4096, 256, 0, stream>>>(x, xb, 1048576);
  cast_kernel<<<2048, 256, 0, stream>>>(Wq, Wqkvb, 524288);
  cast_kernel<<<512, 256, 0, stream>>>(Wk, Wqkvb + (size_t)2048 * 2048, 131072);
  cast_kernel<<<512, 256, 0, stream>>>(Wv, Wqkvb + (size_t)2560 * 2048, 131072);
  cast_kernel<<<2048, 256, 0, stream>>>(Wo, Wob, 524288);
  sincos_kernel<<<512, 256, 0, stream>>>(tab);
  gemm8p<0, 256><<<192, 512, 0, stream>>>(xb, Wqkvb, Qb, Kb, Vt, nullptr, tab);
  attn_kernel<<<1024, 256, 0, stream>>>(Qb, Kb, Vt, AO, counter);
  gemm8p<1, 128><<<256, 512, 0, stream>>>(AO, Wob, nullptr, nullptr, nullptr, out, nullptr);
}

// Round 9
// 192.554 us; speedup vs baseline: 1.1593x; 1.1593x over previous
//
#include <hip/hip_runtime.h>
#include <hip/hip_bf16.h>

typedef __bf16 bf16_t;
typedef __bf16 bf16x8 __attribute__((ext_vector_type(8)));
typedef __bf16 bf16x4 __attribute__((ext_vector_type(4)));
typedef float f32x4 __attribute__((ext_vector_type(4)));
typedef short short4v __attribute__((ext_vector_type(4)));

#define SEQ_T 2048
#define DMODEL 2048
#define NQH 16
#define NKVH 4
#define HDIM 128

__device__ __forceinline__ f32x4 mfma16x16x32(bf16x8 a, bf16x8 b, f32x4 c) {
  return __builtin_amdgcn_mfma_f32_16x16x32_bf16(a, b, c, 0, 0, 0);
}

typedef __attribute__((address_space(3))) void lds_void_t;
typedef __attribute__((address_space(1))) const void gbl_void_t;
__device__ __forceinline__ void gload_lds16(const bf16_t* g, bf16_t* l) {
  __builtin_amdgcn_global_load_lds((gbl_void_t*)g, (lds_void_t*)l, 16, 0, 0);
}
__device__ __forceinline__ void BAR() {
  asm volatile("" ::: "memory");
  __builtin_amdgcn_s_barrier();
  asm volatile("" ::: "memory");
}

// ---------------- cast f32 -> bf16, 8 elems/thread ----------------
__global__ __launch_bounds__(256) void cast_kernel(const float* __restrict__ src,
                                                   bf16_t* __restrict__ dst, int n8) {
  int idx = blockIdx.x * 256 + threadIdx.x;
  if (idx >= n8) return;
  const float4* s = reinterpret_cast<const float4*>(src) + (size_t)idx * 2;
  float4 a = s[0], b = s[1];
  bf16x8 r = {(bf16_t)a.x, (bf16_t)a.y, (bf16_t)a.z, (bf16_t)a.w,
              (bf16_t)b.x, (bf16_t)b.y, (bf16_t)b.z, (bf16_t)b.w};
  reinterpret_cast<bf16x8*>(dst)[idx] = r;
}

// ---------------- RoPE cos/sin table [T][64] (cos, sin) ----------------
__global__ __launch_bounds__(256) void sincos_kernel(float2* __restrict__ tab) {
  int idx = blockIdx.x * 256 + threadIdx.x;  // 2048*64
  int t = idx >> 6, i = idx & 63;
  float inv = powf(10000.0f, -(float)i * (1.0f / 64.0f));
  float ang = (float)t * inv;
  float s, c;
  sincosf(ang, &s, &c);
  tab[idx] = make_float2(c, s);
}

// ---------------- 8-phase 256xBN GEMM: C[m,n] = sum_k A[m,k]*W[n,k] ----------------
// BM=256, BK=64, 8 waves (2M x 4N). Double-buffered LDS, 4 phases per K-tile:
// {ds_read quadrant | issue 1 half-tile prefetch -> raw barrier -> setprio+16 MFMA
// -> barrier}. Counted vmcnt(2) once per K-tile (phase 0) -- loads stay in flight
// across barriers. XOR-swizzled LDS (chunk ^ row&7), pre-swizzled global source.
// MODE 0 (BN=256): QKV epilogue, RoPE fused on Q/K; V transposed + kv-permuted.
// MODE 1 (BN=128): f32 C row-major [M][2048].
template <int MODE, int BN>
__global__ __launch_bounds__(512, 2) void gemm8p(const bf16_t* __restrict__ A,
                                                 const bf16_t* __restrict__ W,
                                                 bf16_t* __restrict__ q_out,
                                                 bf16_t* __restrict__ k_out,
                                                 bf16_t* __restrict__ v_out,
                                                 float* __restrict__ c_out,
                                                 const float2* __restrict__ tab) {
  constexpr int K = 2048;
  constexpr int NT = K / 64;                  // K-tiles
  constexpr int NTX = (MODE == 0) ? (3072 / BN) : (2048 / BN);
  constexpr int WN = BN / 4;                  // wave n-extent
  constexpr int NF = WN / 16;                 // n-frags per wave
  constexpr int NFH = NF / 2;                 // n-frags per phase
  constexpr int NH = 2 + BN / 128;            // half-tiles per K-tile
  const int nwg = gridDim.x;
  const int cpx = nwg >> 3;
  const int id = ((int)blockIdx.x & 7) * cpx + ((int)blockIdx.x >> 3);
  const int m0 = (id / NTX) * 256, n0 = (id % NTX) * BN;
  const int tid = threadIdx.x;
  const int lane = tid & 63, w = tid >> 6;
  const int wr = w >> 2, wc = w & 3;
  const int l15 = lane & 15, g = lane >> 4;
  __shared__ bf16_t smem[2][(256 + BN) * 64];
  f32x4 acc[8][NF] = {};
  bf16x8 af[4][2], bfr[NFH][2];

  auto ISSUE_HALF = [&](int tt, int h) {
    const int k0 = tt * 64;
    bf16_t* base = &smem[tt & 1][0] + ((h < 2) ? h * (128 * 64) : (256 + (h - 2) * 128) * 64);
    const bf16_t* src = (h < 2) ? (A + (size_t)(m0 + h * 128) * K)
                                : (W + (size_t)(n0 + (h - 2) * 128) * K);
#pragma unroll
    for (int i = 0; i < 2; i++) {
      const int rl = i * 64 + (tid >> 3);
      gload_lds16(src + (size_t)rl * K + k0 + (((tid & 7) ^ (rl & 7)) << 3),
                  base + (i * 64 + w * 8) * 64);
    }
  };
  auto RDA = [&](const bf16_t* Ab, int qm) {
#pragma unroll
    for (int fi = 0; fi < 4; fi++) {
      const int row = wr * 128 + qm * 64 + fi * 16 + l15;
#pragma unroll
      for (int ksl = 0; ksl < 2; ksl++)
        af[fi][ksl] = *reinterpret_cast<const bf16x8*>(
            Ab + row * 64 + ((((ksl << 2) + g) ^ (row & 7)) << 3));
    }
  };
  auto RDB = [&](const bf16_t* Bb, int qn) {
#pragma unroll
    for (int fj = 0; fj < NFH; fj++) {
      const int row = wc * WN + qn * (WN / 2) + fj * 16 + l15;
#pragma unroll
      for (int ksl = 0; ksl < 2; ksl++)
        bfr[fj][ksl] = *reinterpret_cast<const bf16x8*>(
            Bb + row * 64 + ((((ksl << 2) + g) ^ (row & 7)) << 3));
    }
  };

#define MMPH(QM, QN)                                                          \
  do {                                                                        \
    __builtin_amdgcn_s_setprio(1);                                            \
    _Pragma("unroll") for (int fi = 0; fi < 4; fi++)                          \
        _Pragma("unroll") for (int fj = 0; fj < NFH; fj++)                    \
            _Pragma("unroll") for (int ksl = 0; ksl < 2; ksl++)               \
                acc[(QM)*4 + fi][(QN)*NFH + fj] = mfma16x16x32(               \
                    af[fi][ksl], bfr[fj][ksl], acc[(QM)*4 + fi][(QN)*NFH + fj]); \
    __builtin_amdgcn_s_setprio(0);                                            \
  } while (0)

  // prologue: stage tile 0
#pragma unroll
  for (int h = 0; h < NH; h++) ISSUE_HALF(0, h);

  for (int t = 0; t < NT; t++) {
    const bf16_t* Ab = &smem[t & 1][0];
    const bf16_t* Bb = Ab + 256 * 64;
    // ---- phase 0: gate tile t, prefetch h0(t+1) ----
    if (t + 1 < NT) {
      ISSUE_HALF(t + 1, 0);
      asm volatile("s_waitcnt vmcnt(2)" ::: "memory");
    } else {
      asm volatile("s_waitcnt vmcnt(0)" ::: "memory");
    }
    BAR();
    RDA(Ab, 0);
    RDB(Bb, 0);
    MMPH(0, 0);
    BAR();
    // ---- phase 1 ----
    RDB(Bb, 1);
    if (t + 1 < NT) ISSUE_HALF(t + 1, 1);
    BAR();
    MMPH(0, 1);
    BAR();
    // ---- phase 2 ----
    RDA(Ab, 1);
    if (t + 1 < NT) ISSUE_HALF(t + 1, 2);
    BAR();
    MMPH(1, 1);
    BAR();
    // ---- phase 3 ----
    RDB(Bb, 0);
    if (t + 1 < NT && NH > 3) ISSUE_HALF(t + 1, 3);
    BAR();
    MMPH(1, 0);
    BAR();
  }
#undef MMPH

  if (MODE == 0) {
#pragma unroll
    for (int fm = 0; fm < 8; fm++) {
      const int r0 = m0 + wr * 128 + fm * 16 + (g << 2);
      const int bb = r0 >> 11;
      const int tt = r0 & 2047;
#pragma unroll
      for (int fn = 0; fn < NF; fn++) {
        const int col = n0 + wc * WN + fn * 16 + l15;
        const f32x4 v = acc[fm][fn];
        if (col < 2048) {  // Q region, RoPE fused
          const int dd = col & 127;
          const float2* tp = tab + (size_t)tt * 64 + (dd >> 1);
          bf16_t* dst = q_out + (((size_t)(bb * NQH + (col >> 7)) * SEQ_T + tt) * HDIM + dd);
#pragma unroll
          for (int i = 0; i < 4; i++) {
            float me = v[i];
            float ot = __shfl_xor(me, 1);
            float2 cs = tp[(size_t)i * 64];
            float r = (dd & 1) ? (me * cs.x + ot * cs.y) : (me * cs.x - ot * cs.y);
            dst[(size_t)i * HDIM] = (bf16_t)r;
          }
        } else if (col < 2560) {  // K region, RoPE fused
          const int dd = col & 127;
          const float2* tp = tab + (size_t)tt * 64 + (dd >> 1);
          bf16_t* dst = k_out + (((size_t)(bb * NKVH + ((col - 2048) >> 7)) * SEQ_T + tt) * HDIM + dd);
#pragma unroll
          for (int i = 0; i < 4; i++) {
            float me = v[i];
            float ot = __shfl_xor(me, 1);
            float2 cs = tp[(size_t)i * 64];
            float r = (dd & 1) ? (me * cs.x + ot * cs.y) : (me * cs.x - ot * cs.y);
            dst[(size_t)i * HDIM] = (bf16_t)r;
          }
        } else {  // V region -> transposed [B,KVh,128,T'] with kv-permutation
          const int vc = col - 2560;
          const int hh = vc >> 7, dd = vc & 127;
          const int tp64 = (tt & ~63) | (((tt >> 2) & 3) << 4) | (((tt >> 4) & 3) << 2);
          bf16x4 pk = {(bf16_t)v[0], (bf16_t)v[1], (bf16_t)v[2], (bf16_t)v[3]};
          *reinterpret_cast<bf16x4*>(v_out + (((size_t)(bb * NKVH + hh) * HDIM + dd) * SEQ_T + tp64)) = pk;
        }
      }
    }
  } else {
#pragma unroll
    for (int fm = 0; fm < 8; fm++) {
      const int r0 = m0 + wr * 128 + fm * 16 + (g << 2);
#pragma unroll
      for (int fn = 0; fn < NF; fn++) {
        const int col = n0 + wc * WN + fn * 16 + l15;
#pragma unroll
        for (int i = 0; i < 4; i++) c_out[(size_t)(r0 + i) * 2048 + col] = acc[fm][fn][i];
      }
    }
  }
}

// ---------------- Flash attention (causal GQA) ----------------
// 512 blocks x 4 waves (2 blocks/CU = 2 independent barrier domains).
// Block (bh, p): paired 64-row q-tiles jH=31-p (heavy), jL=p (light);
// per wave: group A = 16 rows of jH tile, group B = 16 rows of jL tile.
// Compute = 33 units/block (perfect balance). Shared K/V fragment reads when
// both groups active (B active => A unmasked since q0L+63 < 1024 <= q0H).
// KV double-buffered, prefetch-before-compute. Swapped QK^T -> per-lane
// softmax; T13 defer-max; PV fused to 16x16x32 MFMA (vv's 8 kv slots ==
// sv[8s..8s+8] under the kv-permutation; verified fragment algebra).
__global__ __launch_bounds__(256, 2) void attn_kernel(const bf16_t* __restrict__ Qb,
                                                      const bf16_t* __restrict__ Kb,
                                                      const bf16_t* __restrict__ Vt,
                                                      bf16_t* __restrict__ AO) {
  const int bh = blockIdx.x;
  const int b = bh >> 4, h = bh & 15, kvh = h >> 2;
  const int p = blockIdx.y;  // 0..15
  const int jH = 31 - p, jL = p;
  const int q0H = jH * 64, q0L = jL * 64;
  const int tid = threadIdx.x;
  const int lane = tid & 63, w = tid >> 6;  // 4 waves
  const bf16_t* Qp = Qb + (size_t)(b * NQH + h) * SEQ_T * HDIM;
  const bf16_t* Kp = Kb + (size_t)(b * NKVH + kvh) * SEQ_T * HDIM;
  const bf16_t* Vp = Vt + (size_t)(b * NKVH + kvh) * HDIM * SEQ_T;
  __shared__ bf16_t smem[2][16384];  // per buf: Ks [64][128] | Vs [128][64]
  const int l15 = lane & 15, g = lane >> 4;
  const int qrA = q0H + w * 16 + l15;  // heavy-tile q-row
  const int qrB = q0L + w * 16 + l15;  // light-tile q-row
  bf16x8 qfA[4], qfB[4];
#pragma unroll
  for (int c = 0; c < 4; c++) {
    qfA[c] = *reinterpret_cast<const bf16x8*>(Qp + (size_t)qrA * HDIM + c * 32 + (g << 3));
    qfB[c] = *reinterpret_cast<const bf16x8*>(Qp + (size_t)qrB * HDIM + c * 32 + (g << 3));
  }
  f32x4 oA[8] = {}, oB[8] = {};
  float mA = -1e30f, lA = 0.0f, mB = -1e30f, lB = 0.0f;
  const float kscale = 0.08838834764831845f * 1.4426950408889634f;  // 1/sqrt(128)*log2e
  const int wmaxB = q0L + w * 16 + 15;
  const int ntiles = jH + 1;  // KVBLK=64 tiles staged

  auto STAGE = [&](int it, int buf) {
    const int kv0s = it * 64;
    bf16_t* Ks = smem[buf];
    bf16_t* Vs = smem[buf] + 8192;
#pragma unroll
    for (int cc = 0; cc < 4; cc++) {
      const int ck = cc * 256 + tid;
      const int krow = ck >> 4, kg = ck & 15;
      gload_lds16(Kp + (size_t)(kv0s + krow) * HDIM + ((kg ^ (krow & 7)) << 3),
                  Ks + (cc * 256 + w * 64) * 8);
      const int vrow = ck >> 3, vg = ck & 7;
      gload_lds16(Vp + (size_t)vrow * SEQ_T + kv0s + ((vg ^ (vrow & 7)) << 3),
                  Vs + (cc * 256 + w * 64) * 8);
    }
  };

  // softmax: sv (raw scores) -> P packed as bf16x8 pairs (sv[8s..8s+8])
  auto SOFTMAX = [&](float* sv, float& m, float& l, f32x4* o, bf16x8* pc) {
    float tm = sv[0];
#pragma unroll
    for (int j = 1; j < 16; j++) tm = fmaxf(tm, sv[j]);
    tm = fmaxf(tm, __shfl_xor(tm, 16, 64));
    tm = fmaxf(tm, __shfl_xor(tm, 32, 64));
    tm *= kscale;
    if (!__all(tm <= m + 8.0f)) {  // T13 defer-max
      const float mnew = fmaxf(m, tm);
      const float alpha = exp2f(m - mnew);
      m = mnew;
      l *= alpha;
#pragma unroll
      for (int dt = 0; dt < 8; dt++) o[dt] *= alpha;
    }
    float rs = 0.0f;
#pragma unroll
    for (int j = 0; j < 16; j++) {
      sv[j] = exp2f(__builtin_fmaf(sv[j], kscale, -m));
      rs += sv[j];
    }
    rs += __shfl_xor(rs, 16, 64);
    rs += __shfl_xor(rs, 32, 64);
    l += rs;
#pragma unroll
    for (int s = 0; s < 2; s++) {
      bf16x8 t = {(bf16_t)sv[8 * s],     (bf16_t)sv[8 * s + 1], (bf16_t)sv[8 * s + 2],
                  (bf16_t)sv[8 * s + 3], (bf16_t)sv[8 * s + 4], (bf16_t)sv[8 * s + 5],
                  (bf16_t)sv[8 * s + 6], (bf16_t)sv[8 * s + 7]};
      pc[s] = t;
    }
  };

  // single-group compute (A-only), with masking near A's diagonal
  auto COMPUTE1 = [&](const bf16_t* Ks, const bf16_t* Vs, int kv0) {
    float sv[16];
    const bool noMask = (kv0 + 63 <= q0H + w * 16);
    __builtin_amdgcn_s_setprio(1);
#pragma unroll
    for (int ksub = 0; ksub < 4; ksub++) {
      f32x4 sa = {};
      const int krow = ksub * 16 + l15;
#pragma unroll
      for (int ch = 0; ch < 4; ch++) {
        bf16x8 kf = *reinterpret_cast<const bf16x8*>(
            Ks + krow * 128 + ((((ch << 2) + g) ^ (krow & 7)) << 3));
        sa = mfma16x16x32(kf, qfA[ch], sa);
      }
      if (noMask) {
#pragma unroll
        for (int i = 0; i < 4; i++) sv[ksub * 4 + i] = sa[i];
      } else {
        const int dlt = qrA - kv0 - ksub * 16 - (g << 2);
#pragma unroll
        for (int i = 0; i < 4; i++) sv[ksub * 4 + i] = (i <= dlt) ? sa[i] : -3e38f;
      }
    }
    __builtin_amdgcn_s_setprio(0);
    bf16x8 pc[2];
    SOFTMAX(sv, mA, lA, oA, pc);
    __builtin_amdgcn_s_setprio(1);
#pragma unroll
    for (int dt = 0; dt < 8; dt++) {
      const int vrow = dt * 16 + l15;
#pragma unroll
      for (int s = 0; s < 2; s++) {
        bf16x8 vv = *reinterpret_cast<const bf16x8*>(
            Vs + vrow * 64 + (((2 * g + s) ^ (vrow & 7)) << 3));
        oA[dt] = mfma16x16x32(vv, pc[s], oA[dt]);
      }
    }
    __builtin_amdgcn_s_setprio(0);
  };

  // shared-read compute: A (always unmasked here) + B (masked near diagonal)
  auto COMPUTE2 = [&](const bf16_t* Ks, const bf16_t* Vs, int kv0) {
    float svA[16], svB[16];
    const bool noMaskB = (kv0 + 63 <= q0L + w * 16);
    __builtin_amdgcn_s_setprio(1);
#pragma unroll
    for (int ksub = 0; ksub < 4; ksub++) {
      f32x4 sa = {}, sb = {};
      const int krow = ksub * 16 + l15;
#pragma unroll
      for (int ch = 0; ch < 4; ch++) {
        bf16x8 kf = *reinterpret_cast<const bf16x8*>(
            Ks + krow * 128 + ((((ch << 2) + g) ^ (krow & 7)) << 3));
        sa = mfma16x16x32(kf, qfA[ch], sa);
        sb = mfma16x16x32(kf, qfB[ch], sb);
      }
#pragma unroll
      for (int i = 0; i < 4; i++) svA[ksub * 4 + i] = sa[i];
      if (noMaskB) {
#pragma unroll
        for (int i = 0; i < 4; i++) svB[ksub * 4 + i] = sb[i];
      } else {
        const int dltB = qrB - kv0 - ksub * 16 - (g << 2);
#pragma unroll
        for (int i = 0; i < 4; i++) svB[ksub * 4 + i] = (i <= dltB) ? sb[i] : -3e38f;
      }
    }
    __builtin_amdgcn_s_setprio(0);
    bf16x8 pcA[2], pcB[2];
    SOFTMAX(svA, mA, lA, oA, pcA);
    SOFTMAX(svB, mB, lB, oB, pcB);
    __builtin_amdgcn_s_setprio(1);
#pragma unroll
    for (int dt = 0; dt < 8; dt++) {
      const int vrow = dt * 16 + l15;
#pragma unroll
      for (int s = 0; s < 2; s++) {
        bf16x8 vv = *reinterpret_cast<const bf16x8*>(
            Vs + vrow * 64 + (((2 * g + s) ^ (vrow & 7)) << 3));
        oA[dt] = mfma16x16x32(vv, pcA[s], oA[dt]);
        oB[dt] = mfma16x16x32(vv, pcB[s], oB[dt]);
      }
    }
    __builtin_amdgcn_s_setprio(0);
  };

  STAGE(0, 0);
  __syncthreads();  // drains vmcnt(0)
  for (int it = 0; it < ntiles; it++) {
    const int buf = it & 1;
    if (it + 1 < ntiles) STAGE(it + 1, buf ^ 1);  // prefetch flies under compute
    const int kv0 = it * 64;
    const bf16_t* Ks = smem[buf];
    const bf16_t* Vs = smem[buf] + 8192;
    if (kv0 <= wmaxB) {
      COMPUTE2(Ks, Vs, kv0);  // B active => A active & unmasked
    } else {
      COMPUTE1(Ks, Vs, kv0);  // A always active (kv0 <= jH*64 <= qrA tile)
    }
    __syncthreads();  // next tile's stage complete; all waves done with buf
  }
  // epilogue: per-wave LDS slice [16 q][128 d], then coalesced b128 out
  bf16_t* os = &smem[0][0] + w * 2048;
  auto EPI = [&](f32x4* o, float lsum, int q0) {
    const float linv = 1.0f / lsum;
#pragma unroll
    for (int dt = 0; dt < 8; dt++) {
      bf16x4 pk = {(bf16_t)(o[dt][0] * linv), (bf16_t)(o[dt][1] * linv),
                   (bf16_t)(o[dt][2] * linv), (bf16_t)(o[dt][3] * linv)};
      *reinterpret_cast<bf16x4*>(os + l15 * 128 + dt * 16 + (g << 2)) = pk;
    }
    const size_t rowb = (size_t)b * SEQ_T + q0 + w * 16;
#pragma unroll
    for (int kk = 0; kk < 4; kk++) {
      const int c = lane + kk * 64;
      const int q = c >> 4, gc = c & 15;
      *reinterpret_cast<bf16x8*>(AO + (rowb + q) * DMODEL + h * HDIM + gc * 8) =
          *reinterpret_cast<const bf16x8*>(os + q * 128 + gc * 8);
    }
  };
  EPI(oA, lA, q0H);
  EPI(oB, lB, q0L);
}

extern "C" void kernel_launch(void* const* d_in, const int* in_sizes, int n_in,
                              void* d_out, int out_size, void* d_ws, size_t ws_size,
                              hipStream_t stream) {
  const float* x = (const float*)d_in[0];
  const float* Wq = (const float*)d_in[1];
  const float* Wk = (const float*)d_in[2];
  const float* Wv = (const float*)d_in[3];
  const float* Wo = (const float*)d_in[4];
  float* out = (float*)d_out;
  char* ws = (char*)d_ws;
  bf16_t* xb = (bf16_t*)(ws);                         // [4096][2048]        16 MB
  bf16_t* Wqkvb = (bf16_t*)(ws + 16777216);           // [3072][2048]        12 MB
  bf16_t* Wob = (bf16_t*)(ws + 29360128);             // [2048][2048]         8 MB
  bf16_t* Qb = (bf16_t*)(ws + 37748736);              // [2][16][2048][128]  16 MB
  bf16_t* Kb = (bf16_t*)(ws + 54525952);              // [2][4][2048][128]    4 MB
  bf16_t* Vt = (bf16_t*)(ws + 58720256);              // [2][4][128][2048]    4 MB (kv-permuted)
  bf16_t* AO = (bf16_t*)(ws + 62914560);              // [4096][2048]        16 MB
  float2* tab = (float2*)(ws + 79691776);             // [2048][64]           1 MB

  cast_kernel<<<4096, 256, 0, stream>>>(x, xb, 1048576);
  cast_kernel<<<2048, 256, 0, stream>>>(Wq, Wqkvb, 524288);
  cast_kernel<<<512, 256, 0, stream>>>(Wk, Wqkvb + (size_t)2048 * 2048, 131072);
  cast_kernel<<<512, 256, 0, stream>>>(Wv, Wqkvb + (size_t)2560 * 2048, 131072);
  cast_kernel<<<2048, 256, 0, stream>>>(Wo, Wob, 524288);
  sincos_kernel<<<512, 256, 0, stream>>>(tab);
  gemm8p<0, 256><<<192, 512, 0, stream>>>(xb, Wqkvb, Qb, Kb, Vt, nullptr, tab);
  attn_kernel<<<dim3(32, 16), 256, 0, stream>>>(Qb, Kb, Vt, AO);
  gemm8p<1, 128><<<256, 512, 0, stream>>>(AO, Wob, nullptr, nullptr, nullptr, out, nullptr);
}

// Round 10
// 179.571 us; speedup vs baseline: 1.2432x; 1.0723x over previous
//
#include <hip/hip_runtime.h>
#include <hip/hip_bf16.h>

typedef __bf16 bf16_t;
typedef __bf16 bf16x8 __attribute__((ext_vector_type(8)));
typedef __bf16 bf16x4 __attribute__((ext_vector_type(4)));
typedef float f32x4 __attribute__((ext_vector_type(4)));

#define SEQ_T 2048
#define DMODEL 2048
#define NQH 16
#define NKVH 4
#define HDIM 128

__device__ __forceinline__ f32x4 mfma16x16x32(bf16x8 a, bf16x8 b, f32x4 c) {
  return __builtin_amdgcn_mfma_f32_16x16x32_bf16(a, b, c, 0, 0, 0);
}

typedef __attribute__((address_space(3))) void lds_void_t;
typedef __attribute__((address_space(1))) const void gbl_void_t;
__device__ __forceinline__ void gload_lds16(const bf16_t* g, bf16_t* l) {
  __builtin_amdgcn_global_load_lds((gbl_void_t*)g, (lds_void_t*)l, 16, 0, 0);
}
__device__ __forceinline__ void BAR() {
  asm volatile("" ::: "memory");
  __builtin_amdgcn_s_barrier();
  asm volatile("" ::: "memory");
}

// ---------------- fused cast f32 -> bf16 for all 5 inputs ----------------
// vec8 ranges: x[0,1048576) Wq[,1572864) Wk[,1703936) Wv[,1835008) Wo[,2359296)
__global__ __launch_bounds__(256) void cast_all(const float* __restrict__ x,
                                                const float* __restrict__ Wq,
                                                const float* __restrict__ Wk,
                                                const float* __restrict__ Wv,
                                                const float* __restrict__ Wo,
                                                bf16_t* __restrict__ xb,
                                                bf16_t* __restrict__ Wqkvb,
                                                bf16_t* __restrict__ Wob) {
  const int idx = blockIdx.x * 256 + threadIdx.x;  // total 2359296
  const float* src;
  bf16_t* dst;
  if (idx < 1048576) {
    src = x + (size_t)idx * 8;
    dst = xb + (size_t)idx * 8;
  } else if (idx < 1572864) {
    const int r = idx - 1048576;
    src = Wq + (size_t)r * 8;
    dst = Wqkvb + (size_t)r * 8;
  } else if (idx < 1703936) {
    const int r = idx - 1572864;
    src = Wk + (size_t)r * 8;
    dst = Wqkvb + 4194304 + (size_t)r * 8;
  } else if (idx < 1835008) {
    const int r = idx - 1703936;
    src = Wv + (size_t)r * 8;
    dst = Wqkvb + 5242880 + (size_t)r * 8;
  } else {
    const int r = idx - 1835008;
    src = Wo + (size_t)r * 8;
    dst = Wob + (size_t)r * 8;
  }
  const float4* s4 = reinterpret_cast<const float4*>(src);
  float4 a = s4[0], b = s4[1];
  bf16x8 r8 = {(bf16_t)a.x, (bf16_t)a.y, (bf16_t)a.z, (bf16_t)a.w,
               (bf16_t)b.x, (bf16_t)b.y, (bf16_t)b.z, (bf16_t)b.w};
  *reinterpret_cast<bf16x8*>(dst) = r8;
}

// ---------------- RoPE cos/sin table [T][64] (cos, sin) ----------------
__global__ __launch_bounds__(256) void sincos_kernel(float2* __restrict__ tab) {
  int idx = blockIdx.x * 256 + threadIdx.x;  // 2048*64
  int t = idx >> 6, i = idx & 63;
  float inv = powf(10000.0f, -(float)i * (1.0f / 64.0f));
  float ang = (float)t * inv;
  float s, c;
  sincosf(ang, &s, &c);
  tab[idx] = make_float2(c, s);
}

// ---------------- QKV GEMM: 256x192 tile, grid 16x16 = 256 = exact CU cover ----
// BK=64, 8 waves (2M x 4N), wave tile 128x48 (NF=3). Double-buffered LDS (112KB),
// 4 phases per K-tile with uneven MFMA split (16/8/16/8). Staging: A = 2 chunks
// of 128 rows (2 gloads), B = 3 chunks of 64 rows (1 gload) = 7 loads/thread/tile.
// Counted vmcnt(2) once per K-tile. XOR-swizzled LDS, pre-swizzled global source.
// Epilogue: RoPE fused on Q/K; V transposed + kv-permuted.
__global__ __launch_bounds__(512, 2) void gemm_qkv(const bf16_t* __restrict__ A,
                                                   const bf16_t* __restrict__ W,
                                                   bf16_t* __restrict__ q_out,
                                                   bf16_t* __restrict__ k_out,
                                                   bf16_t* __restrict__ v_out,
                                                   const float2* __restrict__ tab) {
  constexpr int K = 2048;
  constexpr int NT = 32;
  const int id = ((int)blockIdx.x & 7) * 32 + ((int)blockIdx.x >> 3);  // XCD swizzle
  const int m0 = (id >> 4) * 256, n0 = (id & 15) * 192;
  const int tid = threadIdx.x;
  const int lane = tid & 63, w = tid >> 6;
  const int wr = w >> 2, wc = w & 3;
  const int l15 = lane & 15, g = lane >> 4;
  __shared__ bf16_t smem[2][(256 + 192) * 64];
  f32x4 acc[8][3] = {};
  bf16x8 af[4][2], bfr[3][2];

  auto ISSUE_A = [&](int tt, int h) {
    bf16_t* base = &smem[tt & 1][0] + h * (128 * 64);
    const bf16_t* src = A + (size_t)(m0 + h * 128) * K + tt * 64;
#pragma unroll
    for (int i = 0; i < 2; i++) {
      const int rl = i * 64 + (tid >> 3);
      gload_lds16(src + (size_t)rl * K + (((tid & 7) ^ (rl & 7)) << 3),
                  base + (i * 64 + w * 8) * 64);
    }
  };
  auto ISSUE_B = [&](int tt, int c) {
    bf16_t* base = &smem[tt & 1][0] + (256 + c * 64) * 64;
    const int rl = tid >> 3;
    const bf16_t* src = W + (size_t)(n0 + c * 64 + rl) * K + tt * 64;
    gload_lds16(src + (((tid & 7) ^ (rl & 7)) << 3), base + (w * 8) * 64);
  };
  auto RDA = [&](const bf16_t* Ab, int qm) {
#pragma unroll
    for (int fi = 0; fi < 4; fi++) {
      const int row = wr * 128 + qm * 64 + fi * 16 + l15;
#pragma unroll
      for (int ksl = 0; ksl < 2; ksl++)
        af[fi][ksl] = *reinterpret_cast<const bf16x8*>(
            Ab + row * 64 + ((((ksl << 2) + g) ^ (row & 7)) << 3));
    }
  };
  auto RDB1 = [&](const bf16_t* Bb, int fj) {
    const int row = wc * 48 + fj * 16 + l15;
#pragma unroll
    for (int ksl = 0; ksl < 2; ksl++)
      bfr[fj][ksl] = *reinterpret_cast<const bf16x8*>(
          Bb + row * 64 + ((((ksl << 2) + g) ^ (row & 7)) << 3));
  };

#define MMX(QM, FJLO, FJHI)                                                   \
  do {                                                                        \
    __builtin_amdgcn_s_setprio(1);                                            \
    _Pragma("unroll") for (int fi = 0; fi < 4; fi++)                          \
        _Pragma("unroll") for (int fj = (FJLO); fj <= (FJHI); fj++)           \
            _Pragma("unroll") for (int ksl = 0; ksl < 2; ksl++)               \
                acc[(QM)*4 + fi][fj] =                                        \
                    mfma16x16x32(af[fi][ksl], bfr[fj][ksl], acc[(QM)*4 + fi][fj]); \
    __builtin_amdgcn_s_setprio(0);                                            \
  } while (0)

  // prologue: stage tile 0 (7 loads/thread)
  ISSUE_A(0, 0);
  ISSUE_A(0, 1);
  ISSUE_B(0, 0);
  ISSUE_B(0, 1);
  ISSUE_B(0, 2);

  for (int t = 0; t < NT; t++) {
    const bf16_t* Ab = &smem[t & 1][0];
    const bf16_t* Bb = Ab + 256 * 64;
    // ---- phase 0: gate tile t (9 outstanding -> keep 2), prefetch A0(t+1) ----
    if (t + 1 < NT) {
      ISSUE_A(t + 1, 0);
      asm volatile("s_waitcnt vmcnt(2)" ::: "memory");
    } else {
      asm volatile("s_waitcnt vmcnt(0)" ::: "memory");
    }
    BAR();
    RDA(Ab, 0);
    RDB1(Bb, 0);
    RDB1(Bb, 1);
    MMX(0, 0, 1);
    BAR();
    // ---- phase 1 ----
    RDB1(Bb, 2);
    if (t + 1 < NT) ISSUE_A(t + 1, 1);
    BAR();
    MMX(0, 2, 2);
    BAR();
    // ---- phase 2 ----
    RDA(Ab, 1);
    if (t + 1 < NT) {
      ISSUE_B(t + 1, 0);
      ISSUE_B(t + 1, 1);
    }
    BAR();
    MMX(1, 0, 1);
    BAR();
    // ---- phase 3 ----
    if (t + 1 < NT) ISSUE_B(t + 1, 2);
    BAR();
    MMX(1, 2, 2);
    BAR();
  }
#undef MMX

#pragma unroll
  for (int fm = 0; fm < 8; fm++) {
    const int r0 = m0 + wr * 128 + fm * 16 + (g << 2);
    const int bb = r0 >> 11;
    const int tt = r0 & 2047;
#pragma unroll
    for (int fn = 0; fn < 3; fn++) {
      const int col = n0 + wc * 48 + fn * 16 + l15;
      const f32x4 v = acc[fm][fn];
      if (col < 2048) {  // Q region, RoPE fused
        const int dd = col & 127;
        const float2* tp = tab + (size_t)tt * 64 + (dd >> 1);
        bf16_t* dst = q_out + (((size_t)(bb * NQH + (col >> 7)) * SEQ_T + tt) * HDIM + dd);
#pragma unroll
        for (int i = 0; i < 4; i++) {
          float me = v[i];
          float ot = __shfl_xor(me, 1);
          float2 cs = tp[(size_t)i * 64];
          float r = (dd & 1) ? (me * cs.x + ot * cs.y) : (me * cs.x - ot * cs.y);
          dst[(size_t)i * HDIM] = (bf16_t)r;
        }
      } else if (col < 2560) {  // K region, RoPE fused
        const int dd = col & 127;
        const float2* tp = tab + (size_t)tt * 64 + (dd >> 1);
        bf16_t* dst = k_out + (((size_t)(bb * NKVH + ((col - 2048) >> 7)) * SEQ_T + tt) * HDIM + dd);
#pragma unroll
        for (int i = 0; i < 4; i++) {
          float me = v[i];
          float ot = __shfl_xor(me, 1);
          float2 cs = tp[(size_t)i * 64];
          float r = (dd & 1) ? (me * cs.x + ot * cs.y) : (me * cs.x - ot * cs.y);
          dst[(size_t)i * HDIM] = (bf16_t)r;
        }
      } else {  // V region -> transposed [B,KVh,128,T'] with kv-permutation
        const int vc = col - 2560;
        const int hh = vc >> 7, dd = vc & 127;
        const int tp64 = (tt & ~63) | (((tt >> 2) & 3) << 4) | (((tt >> 4) & 3) << 2);
        bf16x4 pk = {(bf16_t)v[0], (bf16_t)v[1], (bf16_t)v[2], (bf16_t)v[3]};
        *reinterpret_cast<bf16x4*>(v_out + (((size_t)(bb * NKVH + hh) * HDIM + dd) * SEQ_T + tp64)) = pk;
      }
    }
  }
}

// ---------------- Out GEMM: 256x128 tile, grid 16x16 = 256 ----------------
// (unchanged working 8-phase structure; f32 C row-major [4096][2048])
__global__ __launch_bounds__(512, 2) void gemm_out(const bf16_t* __restrict__ A,
                                                   const bf16_t* __restrict__ W,
                                                   float* __restrict__ c_out) {
  constexpr int K = 2048;
  constexpr int NT = 32;
  const int id = ((int)blockIdx.x & 7) * 32 + ((int)blockIdx.x >> 3);
  const int m0 = (id >> 4) * 256, n0 = (id & 15) * 128;
  const int tid = threadIdx.x;
  const int lane = tid & 63, w = tid >> 6;
  const int wr = w >> 2, wc = w & 3;
  const int l15 = lane & 15, g = lane >> 4;
  __shared__ bf16_t smem[2][(256 + 128) * 64];
  f32x4 acc[8][2] = {};
  bf16x8 af[4][2], bfr[1][2];

  auto ISSUE_HALF = [&](int tt, int h) {
    const int k0 = tt * 64;
    bf16_t* base = &smem[tt & 1][0] + ((h < 2) ? h * (128 * 64) : 256 * 64);
    const bf16_t* src = (h < 2) ? (A + (size_t)(m0 + h * 128) * K)
                                : (W + (size_t)n0 * K);
#pragma unroll
    for (int i = 0; i < 2; i++) {
      const int rl = i * 64 + (tid >> 3);
      gload_lds16(src + (size_t)rl * K + k0 + (((tid & 7) ^ (rl & 7)) << 3),
                  base + (i * 64 + w * 8) * 64);
    }
  };
  auto RDA = [&](const bf16_t* Ab, int qm) {
#pragma unroll
    for (int fi = 0; fi < 4; fi++) {
      const int row = wr * 128 + qm * 64 + fi * 16 + l15;
#pragma unroll
      for (int ksl = 0; ksl < 2; ksl++)
        af[fi][ksl] = *reinterpret_cast<const bf16x8*>(
            Ab + row * 64 + ((((ksl << 2) + g) ^ (row & 7)) << 3));
    }
  };
  auto RDB = [&](const bf16_t* Bb, int qn) {
    const int row = wc * 32 + qn * 16 + l15;
#pragma unroll
    for (int ksl = 0; ksl < 2; ksl++)
      bfr[0][ksl] = *reinterpret_cast<const bf16x8*>(
          Bb + row * 64 + ((((ksl << 2) + g) ^ (row & 7)) << 3));
  };

#define MMPH(QM, QN)                                                          \
  do {                                                                        \
    __builtin_amdgcn_s_setprio(1);                                            \
    _Pragma("unroll") for (int fi = 0; fi < 4; fi++)                          \
        _Pragma("unroll") for (int ksl = 0; ksl < 2; ksl++)                   \
            acc[(QM)*4 + fi][(QN)] =                                          \
                mfma16x16x32(af[fi][ksl], bfr[0][ksl], acc[(QM)*4 + fi][(QN)]); \
    __builtin_amdgcn_s_setprio(0);                                            \
  } while (0)

#pragma unroll
  for (int h = 0; h < 3; h++) ISSUE_HALF(0, h);

  for (int t = 0; t < NT; t++) {
    const bf16_t* Ab = &smem[t & 1][0];
    const bf16_t* Bb = Ab + 256 * 64;
    if (t + 1 < NT) {
      ISSUE_HALF(t + 1, 0);
      asm volatile("s_waitcnt vmcnt(2)" ::: "memory");
    } else {
      asm volatile("s_waitcnt vmcnt(0)" ::: "memory");
    }
    BAR();
    RDA(Ab, 0);
    RDB(Bb, 0);
    MMPH(0, 0);
    BAR();
    RDB(Bb, 1);
    if (t + 1 < NT) ISSUE_HALF(t + 1, 1);
    BAR();
    MMPH(0, 1);
    BAR();
    RDA(Ab, 1);
    if (t + 1 < NT) ISSUE_HALF(t + 1, 2);
    BAR();
    MMPH(1, 1);
    BAR();
    RDB(Bb, 0);
    BAR();
    MMPH(1, 0);
    BAR();
  }
#undef MMPH

#pragma unroll
  for (int fm = 0; fm < 8; fm++) {
    const int r0 = m0 + wr * 128 + fm * 16 + (g << 2);
#pragma unroll
    for (int fn = 0; fn < 2; fn++) {
      const int col = n0 + wc * 32 + fn * 16 + l15;
#pragma unroll
      for (int i = 0; i < 4; i++) c_out[(size_t)(r0 + i) * 2048 + col] = acc[fm][fn][i];
    }
  }
}

// ---------------- Flash attention (causal GQA) ---------------- (unchanged R9)
__global__ __launch_bounds__(256, 2) void attn_kernel(const bf16_t* __restrict__ Qb,
                                                      const bf16_t* __restrict__ Kb,
                                                      const bf16_t* __restrict__ Vt,
                                                      bf16_t* __restrict__ AO) {
  const int bh = blockIdx.x;
  const int b = bh >> 4, h = bh & 15, kvh = h >> 2;
  const int p = blockIdx.y;  // 0..15
  const int jH = 31 - p, jL = p;
  const int q0H = jH * 64, q0L = jL * 64;
  const int tid = threadIdx.x;
  const int lane = tid & 63, w = tid >> 6;  // 4 waves
  const bf16_t* Qp = Qb + (size_t)(b * NQH + h) * SEQ_T * HDIM;
  const bf16_t* Kp = Kb + (size_t)(b * NKVH + kvh) * SEQ_T * HDIM;
  const bf16_t* Vp = Vt + (size_t)(b * NKVH + kvh) * HDIM * SEQ_T;
  __shared__ bf16_t smem[2][16384];  // per buf: Ks [64][128] | Vs [128][64]
  const int l15 = lane & 15, g = lane >> 4;
  const int qrA = q0H + w * 16 + l15;  // heavy-tile q-row
  const int qrB = q0L + w * 16 + l15;  // light-tile q-row
  bf16x8 qfA[4], qfB[4];
#pragma unroll
  for (int c = 0; c < 4; c++) {
    qfA[c] = *reinterpret_cast<const bf16x8*>(Qp + (size_t)qrA * HDIM + c * 32 + (g << 3));
    qfB[c] = *reinterpret_cast<const bf16x8*>(Qp + (size_t)qrB * HDIM + c * 32 + (g << 3));
  }
  f32x4 oA[8] = {}, oB[8] = {};
  float mA = -1e30f, lA = 0.0f, mB = -1e30f, lB = 0.0f;
  const float kscale = 0.08838834764831845f * 1.4426950408889634f;  // 1/sqrt(128)*log2e
  const int wmaxB = q0L + w * 16 + 15;
  const int ntiles = jH + 1;  // KVBLK=64 tiles staged

  auto STAGE = [&](int it, int buf) {
    const int kv0s = it * 64;
    bf16_t* Ks = smem[buf];
    bf16_t* Vs = smem[buf] + 8192;
#pragma unroll
    for (int cc = 0; cc < 4; cc++) {
      const int ck = cc * 256 + tid;
      const int krow = ck >> 4, kg = ck & 15;
      gload_lds16(Kp + (size_t)(kv0s + krow) * HDIM + ((kg ^ (krow & 7)) << 3),
                  Ks + (cc * 256 + w * 64) * 8);
      const int vrow = ck >> 3, vg = ck & 7;
      gload_lds16(Vp + (size_t)vrow * SEQ_T + kv0s + ((vg ^ (vrow & 7)) << 3),
                  Vs + (cc * 256 + w * 64) * 8);
    }
  };

  auto SOFTMAX = [&](float* sv, float& m, float& l, f32x4* o, bf16x8* pc) {
    float tm = sv[0];
#pragma unroll
    for (int j = 1; j < 16; j++) tm = fmaxf(tm, sv[j]);
    tm = fmaxf(tm, __shfl_xor(tm, 16, 64));
    tm = fmaxf(tm, __shfl_xor(tm, 32, 64));
    tm *= kscale;
    if (!__all(tm <= m + 8.0f)) {  // T13 defer-max
      const float mnew = fmaxf(m, tm);
      const float alpha = exp2f(m - mnew);
      m = mnew;
      l *= alpha;
#pragma unroll
      for (int dt = 0; dt < 8; dt++) o[dt] *= alpha;
    }
    float rs = 0.0f;
#pragma unroll
    for (int j = 0; j < 16; j++) {
      sv[j] = exp2f(__builtin_fmaf(sv[j], kscale, -m));
      rs += sv[j];
    }
    rs += __shfl_xor(rs, 16, 64);
    rs += __shfl_xor(rs, 32, 64);
    l += rs;
#pragma unroll
    for (int s = 0; s < 2; s++) {
      bf16x8 t = {(bf16_t)sv[8 * s],     (bf16_t)sv[8 * s + 1], (bf16_t)sv[8 * s + 2],
                  (bf16_t)sv[8 * s + 3], (bf16_t)sv[8 * s + 4], (bf16_t)sv[8 * s + 5],
                  (bf16_t)sv[8 * s + 6], (bf16_t)sv[8 * s + 7]};
      pc[s] = t;
    }
  };

  auto COMPUTE1 = [&](const bf16_t* Ks, const bf16_t* Vs, int kv0) {
    float sv[16];
    const bool noMask = (kv0 + 63 <= q0H + w * 16);
    __builtin_amdgcn_s_setprio(1);
#pragma unroll
    for (int ksub = 0; ksub < 4; ksub++) {
      f32x4 sa = {};
      const int krow = ksub * 16 + l15;
#pragma unroll
      for (int ch = 0; ch < 4; ch++) {
        bf16x8 kf = *reinterpret_cast<const bf16x8*>(
            Ks + krow * 128 + ((((ch << 2) + g) ^ (krow & 7)) << 3));
        sa = mfma16x16x32(kf, qfA[ch], sa);
      }
      if (noMask) {
#pragma unroll
        for (int i = 0; i < 4; i++) sv[ksub * 4 + i] = sa[i];
      } else {
        const int dlt = qrA - kv0 - ksub * 16 - (g << 2);
#pragma unroll
        for (int i = 0; i < 4; i++) sv[ksub * 4 + i] = (i <= dlt) ? sa[i] : -3e38f;
      }
    }
    __builtin_amdgcn_s_setprio(0);
    bf16x8 pc[2];
    SOFTMAX(sv, mA, lA, oA, pc);
    __builtin_amdgcn_s_setprio(1);
#pragma unroll
    for (int dt = 0; dt < 8; dt++) {
      const int vrow = dt * 16 + l15;
#pragma unroll
      for (int s = 0; s < 2; s++) {
        bf16x8 vv = *reinterpret_cast<const bf16x8*>(
            Vs + vrow * 64 + (((2 * g + s) ^ (vrow & 7)) << 3));
        oA[dt] = mfma16x16x32(vv, pc[s], oA[dt]);
      }
    }
    __builtin_amdgcn_s_setprio(0);
  };

  auto COMPUTE2 = [&](const bf16_t* Ks, const bf16_t* Vs, int kv0) {
    float svA[16], svB[16];
    const bool noMaskB = (kv0 + 63 <= q0L + w * 16);
    __builtin_amdgcn_s_setprio(1);
#pragma unroll
    for (int ksub = 0; ksub < 4; ksub++) {
      f32x4 sa = {}, sb = {};
      const int krow = ksub * 16 + l15;
#pragma unroll
      for (int ch = 0; ch < 4; ch++) {
        bf16x8 kf = *reinterpret_cast<const bf16x8*>(
            Ks + krow * 128 + ((((ch << 2) + g) ^ (krow & 7)) << 3));
        sa = mfma16x16x32(kf, qfA[ch], sa);
        sb = mfma16x16x32(kf, qfB[ch], sb);
      }
#pragma unroll
      for (int i = 0; i < 4; i++) svA[ksub * 4 + i] = sa[i];
      if (noMaskB) {
#pragma unroll
        for (int i = 0; i < 4; i++) svB[ksub * 4 + i] = sb[i];
      } else {
        const int dltB = qrB - kv0 - ksub * 16 - (g << 2);
#pragma unroll
        for (int i = 0; i < 4; i++) svB[ksub * 4 + i] = (i <= dltB) ? sb[i] : -3e38f;
      }
    }
    __builtin_amdgcn_s_setprio(0);
    bf16x8 pcA[2], pcB[2];
    SOFTMAX(svA, mA, lA, oA, pcA);
    SOFTMAX(svB, mB, lB, oB, pcB);
    __builtin_amdgcn_s_setprio(1);
#pragma unroll
    for (int dt = 0; dt < 8; dt++) {
      const int vrow = dt * 16 + l15;
#pragma unroll
      for (int s = 0; s < 2; s++) {
        bf16x8 vv = *reinterpret_cast<const bf16x8*>(
            Vs + vrow * 64 + (((2 * g + s) ^ (vrow & 7)) << 3));
        oA[dt] = mfma16x16x32(vv, pcA[s], oA[dt]);
        oB[dt] = mfma16x16x32(vv, pcB[s], oB[dt]);
      }
    }
    __builtin_amdgcn_s_setprio(0);
  };

  STAGE(0, 0);
  __syncthreads();  // drains vmcnt(0)
  for (int it = 0; it < ntiles; it++) {
    const int buf = it & 1;
    if (it + 1 < ntiles) STAGE(it + 1, buf ^ 1);  // prefetch flies under compute
    const int kv0 = it * 64;
    const bf16_t* Ks = smem[buf];
    const bf16_t* Vs = smem[buf] + 8192;
    if (kv0 <= wmaxB) {
      COMPUTE2(Ks, Vs, kv0);  // B active => A active & unmasked
    } else {
      COMPUTE1(Ks, Vs, kv0);
    }
    __syncthreads();  // next tile's stage complete; all waves done with buf
  }
  bf16_t* os = &smem[0][0] + w * 2048;
  auto EPI = [&](f32x4* o, float lsum, int q0) {
    const float linv = 1.0f / lsum;
#pragma unroll
    for (int dt = 0; dt < 8; dt++) {
      bf16x4 pk = {(bf16_t)(o[dt][0] * linv), (bf16_t)(o[dt][1] * linv),
                   (bf16_t)(o[dt][2] * linv), (bf16_t)(o[dt][3] * linv)};
      *reinterpret_cast<bf16x4*>(os + l15 * 128 + dt * 16 + (g << 2)) = pk;
    }
    const size_t rowb = (size_t)b * SEQ_T + q0 + w * 16;
#pragma unroll
    for (int kk = 0; kk < 4; kk++) {
      const int c = lane + kk * 64;
      const int q = c >> 4, gc = c & 15;
      *reinterpret_cast<bf16x8*>(AO + (rowb + q) * DMODEL + h * HDIM + gc * 8) =
          *reinterpret_cast<const bf16x8*>(os + q * 128 + gc * 8);
    }
  };
  EPI(oA, lA, q0H);
  EPI(oB, lB, q0L);
}

extern "C" void kernel_launch(void* const* d_in, const int* in_sizes, int n_in,
                              void* d_out, int out_size, void* d_ws, size_t ws_size,
                              hipStream_t stream) {
  const float* x = (const float*)d_in[0];
  const float* Wq = (const float*)d_in[1];
  const float* Wk = (const float*)d_in[2];
  const float* Wv = (const float*)d_in[3];
  const float* Wo = (const float*)d_in[4];
  float* out = (float*)d_out;
  char* ws = (char*)d_ws;
  bf16_t* xb = (bf16_t*)(ws);                         // [4096][2048]        16 MB
  bf16_t* Wqkvb = (bf16_t*)(ws + 16777216);           // [3072][2048]        12 MB
  bf16_t* Wob = (bf16_t*)(ws + 29360128);             // [2048][2048]         8 MB
  bf16_t* Qb = (bf16_t*)(ws + 37748736);              // [2][16][2048][128]  16 MB
  bf16_t* Kb = (bf16_t*)(ws + 54525952);              // [2][4][2048][128]    4 MB
  bf16_t* Vt = (bf16_t*)(ws + 58720256);              // [2][4][128][2048]    4 MB (kv-permuted)
  bf16_t* AO = (bf16_t*)(ws + 62914560);              // [4096][2048]        16 MB
  float2* tab = (float2*)(ws + 79691776);             // [2048][64]           1 MB

  cast_all<<<9216, 256, 0, stream>>>(x, Wq, Wk, Wv, Wo, xb, Wqkvb, Wob);
  sincos_kernel<<<512, 256, 0, stream>>>(tab);
  gemm_qkv<<<256, 512, 0, stream>>>(xb, Wqkvb, Qb, Kb, Vt, tab);
  attn_kernel<<<dim3(32, 16), 256, 0, stream>>>(Qb, Kb, Vt, AO);
  gemm_out<<<256, 512, 0, stream>>>(AO, Wob, out);
}